// Round 1
// 214.265 us; speedup vs baseline: 1.0837x; 1.0837x over previous
//
#include <hip/hip_runtime.h>
#include <math.h>

#define NN 32
#define CC 64
#define HWD 12544
#define HW4 3136              // float4 groups per (n,c)
#define CHUNKS_PER_N 49       // 3136 / 64, exact
#define NCHUNK (NN * CHUNKS_PER_N)   // 1568
#define HID 8
#define OUTD 256
#define T_INV 0.1f
#define GAMMA_F (12544.0f / 3.0f)
#define TOT4 (NN * CC * HW4)  // 6422528 float4s total

typedef float v4f __attribute__((ext_vector_type(4)));

__device__ __forceinline__ float wave_sum(float v) {
    #pragma unroll
    for (int off = 32; off; off >>= 1) v += __shfl_down(v, off, 64);
    return v;
}

// k1: one single-wave block per 64-group chunk (1568 blocks, zero dead lanes,
// balanced ~6 blocks/CU). Per-thread: 64 independent float4 loads, conv score
// thread-local -> e = exp(s/T) written to ws (k3 never recomputes the conv).
// Pool partials reduced with a halving butterfly: 63 shfls total instead of
// 64 x 6 = 384. Lane L ends holding the chunk total for channel bitrev6(L).
__global__ __launch_bounds__(64) void k1_stats(const float* __restrict__ x,
        const float* __restrict__ cw, const float* __restrict__ cb,
        float* __restrict__ pp, float* __restrict__ se,
        float* __restrict__ ews) {
    int lane = threadIdx.x;                 // 0..63
    int g = blockIdx.x;                     // chunk id 0..1567
    int n = g / CHUNKS_PER_N;
    int j = g - n * CHUNKS_PER_N;

    const float4* x4 = (const float4*)x + (size_t)n * CC * HW4 + j * 64 + lane;

    float p64[64];
    float4 cacc = make_float4(0.f, 0.f, 0.f, 0.f);
    #pragma unroll
    for (int c = 0; c < CC; ++c) {
        float4 v = x4[(size_t)c * HW4];
        float ww = cw[c];                   // uniform -> s_load
        cacc.x += v.x * ww; cacc.y += v.y * ww;
        cacc.z += v.z * ww; cacc.w += v.w * ww;
        p64[c] = (v.x + v.y) + (v.z + v.w);
    }

    float bb = cb[0];
    // no max-subtraction: |s/T| < ~1 (w ~ 0.1*N(0,1)); same math as before.
    float4 e;
    e.x = __expf((cacc.x + bb) * T_INV);
    e.y = __expf((cacc.y + bb) * T_INV);
    e.z = __expf((cacc.z + bb) * T_INV);
    e.w = __expf((cacc.w + bb) * T_INV);
    ((float4*)ews)[(size_t)n * HW4 + j * 64 + lane] = e;

    float se_acc = wave_sum((e.x + e.y) + (e.z + e.w));
    if (lane == 0) se[g] = se_acc;

    // halving butterfly: round S exchanges the dead half of the array with
    // lane^(1<<S) and folds; array length 64->32->16->8->4->2->1.
    #define BFLY_ROUND(S, LEN)                                         \
    {                                                                  \
        bool up = (lane >> (S)) & 1;                                   \
        _Pragma("unroll")                                              \
        for (int q = 0; q < (LEN); ++q) {                              \
            float send = up ? p64[q] : p64[q + (LEN)];                 \
            float recv = __shfl_xor(send, 1 << (S), 64);               \
            p64[q] = (up ? p64[q + (LEN)] : p64[q]) + recv;            \
        }                                                              \
    }
    BFLY_ROUND(0, 32)
    BFLY_ROUND(1, 16)
    BFLY_ROUND(2, 8)
    BFLY_ROUND(3, 4)
    BFLY_ROUND(4, 2)
    BFLY_ROUND(5, 1)
    #undef BFLY_ROUND

    int ch = (int)(__brev((unsigned)lane) >> 26);   // bitrev6(lane)
    pp[g * CC + ch] = p64[0];
}

// k2: per-n finish reductions, tiny MLP, a/b coefficient tables, softmax scale.
__global__ __launch_bounds__(256) void k2_mlp(const float* __restrict__ pp,
        const float* __restrict__ se, const float* __restrict__ w1,
        const float* __restrict__ b1, const float* __restrict__ w2,
        const float* __restrict__ b2, float* __restrict__ a_ws,
        float* __restrict__ b_ws, float* __restrict__ scale) {
    int n = blockIdx.x, t = threadIdx.x;
    __shared__ float p[CC];
    __shared__ float h[HID];
    if (t < CC) {
        float acc = 0.f;
        #pragma unroll
        for (int j = 0; j < CHUNKS_PER_N; ++j)
            acc += pp[(n * CHUNKS_PER_N + j) * CC + t];
        p[t] = acc * (1.0f / HWD);
    }
    if (t == 0) {
        float ss = 0.f;
        #pragma unroll
        for (int j = 0; j < CHUNKS_PER_N; ++j) ss += se[n * CHUNKS_PER_N + j];
        scale[n] = GAMMA_F / ss;
    }
    __syncthreads();
    if (t < HID) {
        float acc = b1[t];
        #pragma unroll 8
        for (int c = 0; c < CC; ++c) acc += p[c] * w1[c * HID + t];
        h[t] = fmaxf(acc, 0.f);
    }
    __syncthreads();
    float o = b2[t];
    #pragma unroll
    for (int j = 0; j < HID; ++j) o += h[j] * w2[j * OUTD + t];
    float theta = 2.f / (1.f + __expf(-o)) - 1.f;   // 2*sigmoid-1
    int k = t >> 7, c = (t >> 1) & 63, d = t & 1;
    float init = (k == 0) ? 1.f : 0.f;              // init_alpha==init_beta==[1,0]
    int idx = n * 128 + k * 64 + c;
    if (d == 0) a_ws[idx] = init + theta;           // LAMBDA_ALPHA = 1.0
    else        b_ws[idx] = init + 0.5f * theta;    // LAMBDA_BETA  = 0.5
}

// k3: pure streaming. One thread per output float4 (6.4M threads, 25088
// blocks -> ~100 blocks/CU, perfectly balanced, no LDS, no barriers).
// Reads x once + cached e/coeffs, 16 FLOPs, nontemporal store.
__global__ __launch_bounds__(256) void k3_final(const float* __restrict__ x,
        const float* __restrict__ ews, const float* __restrict__ a_ws,
        const float* __restrict__ b_ws, const float* __restrict__ scale,
        float* __restrict__ out) {
    unsigned f = blockIdx.x * 256u + threadIdx.x;   // < TOT4 exactly
    unsigned n = f / (CC * HW4);                    // const-divisor magic mul
    unsigned r = f - n * (CC * HW4);
    unsigned c = r / HW4;
    unsigned g = r - c * HW4;

    float4 v = ((const float4*)x)[f];
    float4 e = ((const float4*)ews)[n * HW4 + g];
    float sc = scale[n];                            // L1-hot
    float a0 = a_ws[n * 128 + c];
    float a1 = a_ws[n * 128 + 64 + c];
    float b0 = b_ws[n * 128 + c];
    float b1v = b_ws[n * 128 + 64 + c];

    float spx = fminf(sc * e.x, 1.f);
    float spy = fminf(sc * e.y, 1.f);
    float spz = fminf(sc * e.z, 1.f);
    float spw = fminf(sc * e.w, 1.f);

    v4f r4;
    r4.x = spx * fmaxf(v.x * a0 + b0, v.x * a1 + b1v);
    r4.y = spy * fmaxf(v.y * a0 + b0, v.y * a1 + b1v);
    r4.z = spz * fmaxf(v.z * a0 + b0, v.z * a1 + b1v);
    r4.w = spw * fmaxf(v.w * a0 + b0, v.w * a1 + b1v);
    __builtin_nontemporal_store(r4, &((v4f*)out)[f]);
}

extern "C" void kernel_launch(void* const* d_in, const int* in_sizes, int n_in,
                              void* d_out, int out_size, void* d_ws, size_t ws_size,
                              hipStream_t stream) {
    const float* x      = (const float*)d_in[0];
    const float* conv_w = (const float*)d_in[1];
    const float* conv_b = (const float*)d_in[2];
    const float* w1     = (const float*)d_in[3];
    const float* b1     = (const float*)d_in[4];
    const float* w2     = (const float*)d_in[5];
    const float* b2     = (const float*)d_in[6];
    float* out = (float*)d_out;

    float* ws   = (float*)d_ws;
    float* pp   = ws;                       // NCHUNK*CC = 100352
    float* se   = pp + NCHUNK * CC;         // NCHUNK   = 1568
    float* a_ws = se + NCHUNK;              // N*K*C    = 4096
    float* b_ws = a_ws + NN * 2 * CC;       // 4096
    float* scl  = b_ws + NN * 2 * CC;       // 32
    float* ews  = scl + NN;                 // N*HWD    = 401408 (16B-aligned)

    k1_stats<<<NCHUNK,      64, 0, stream>>>(x, conv_w, conv_b, pp, se, ews);
    k2_mlp  <<<NN,         256, 0, stream>>>(pp, se, w1, b1, w2, b2, a_ws, b_ws, scl);
    k3_final<<<TOT4 / 256, 256, 0, stream>>>(x, ews, a_ws, b_ws, scl, out);
}

// Round 2
// 213.848 us; speedup vs baseline: 1.0858x; 1.0019x over previous
//
#include <hip/hip_runtime.h>
#include <math.h>

#define NN 32
#define CC 64
#define HWD 12544
#define HW4 3136              // float4 groups per (n,c)
#define CHUNKS_PER_N 49       // 3136 / 64, exact
#define NCHUNK (NN * CHUNKS_PER_N)   // 1568
#define HID 8
#define OUTD 256
#define T_INV 0.1f
#define GAMMA_F (12544.0f / 3.0f)
#define ROW4 (CC * HW4)       // 200704 float4s per sample

typedef float v4f __attribute__((ext_vector_type(4)));

__device__ __forceinline__ float wave_sum(float v) {
    #pragma unroll
    for (int off = 32; off; off >>= 1) v += __shfl_down(v, off, 64);
    return v;
}

// k1: one single-wave block per 64-group chunk (1568 blocks, zero dead lanes,
// all co-resident -> no tail; purely HBM-read-bound ~16-18us). Conv score is
// thread-local -> e = exp(s/T) written to ws (k3 never recomputes the conv).
// Pool partials reduced with a halving butterfly: 63 shfls total.
// Lane L ends holding the chunk total for channel bitrev6(L).
__global__ __launch_bounds__(64) void k1_stats(const float* __restrict__ x,
        const float* __restrict__ cw, const float* __restrict__ cb,
        float* __restrict__ pp, float* __restrict__ se,
        float* __restrict__ ews) {
    int lane = threadIdx.x;                 // 0..63
    int g = blockIdx.x;                     // chunk id 0..1567
    int n = g / CHUNKS_PER_N;
    int j = g - n * CHUNKS_PER_N;

    const float4* x4 = (const float4*)x + (size_t)n * ROW4 + j * 64 + lane;

    float p64[64];
    float4 cacc = make_float4(0.f, 0.f, 0.f, 0.f);
    #pragma unroll
    for (int c = 0; c < CC; ++c) {
        float4 v = x4[(size_t)c * HW4];
        float ww = cw[c];                   // uniform -> s_load
        cacc.x += v.x * ww; cacc.y += v.y * ww;
        cacc.z += v.z * ww; cacc.w += v.w * ww;
        p64[c] = (v.x + v.y) + (v.z + v.w);
    }

    float bb = cb[0];
    // no max-subtraction: |s/T| < ~1 (w ~ 0.1*N(0,1)); same math as reference
    // within fp32 tolerance.
    float4 e;
    e.x = __expf((cacc.x + bb) * T_INV);
    e.y = __expf((cacc.y + bb) * T_INV);
    e.z = __expf((cacc.z + bb) * T_INV);
    e.w = __expf((cacc.w + bb) * T_INV);
    ((float4*)ews)[(size_t)n * HW4 + j * 64 + lane] = e;

    float se_acc = wave_sum((e.x + e.y) + (e.z + e.w));
    if (lane == 0) se[g] = se_acc;

    // halving butterfly: round S exchanges the dead half of the array with
    // lane^(1<<S) and folds; array length 64->32->16->8->4->2->1.
    #define BFLY_ROUND(S, LEN)                                         \
    {                                                                  \
        bool up = (lane >> (S)) & 1;                                   \
        _Pragma("unroll")                                              \
        for (int q = 0; q < (LEN); ++q) {                              \
            float send = up ? p64[q] : p64[q + (LEN)];                 \
            float recv = __shfl_xor(send, 1 << (S), 64);               \
            p64[q] = (up ? p64[q + (LEN)] : p64[q]) + recv;            \
        }                                                              \
    }
    BFLY_ROUND(0, 32)
    BFLY_ROUND(1, 16)
    BFLY_ROUND(2, 8)
    BFLY_ROUND(3, 4)
    BFLY_ROUND(4, 2)
    BFLY_ROUND(5, 1)
    #undef BFLY_ROUND

    int ch = (int)(__brev((unsigned)lane) >> 26);   // bitrev6(lane)
    pp[g * CC + ch] = p64[0];
}

// k2: per-n finish reductions, tiny MLP, packed {a0,b0,a1,b1} coefficient
// table (one float4 per (n,c)), softmax scale. se-sum is wave-parallel on
// wave 1 while wave 0 does the pool reduction.
__global__ __launch_bounds__(256) void k2_mlp(const float* __restrict__ pp,
        const float* __restrict__ se, const float* __restrict__ w1,
        const float* __restrict__ b1, const float* __restrict__ w2,
        const float* __restrict__ b2, float* __restrict__ coef,
        float* __restrict__ scale) {
    int n = blockIdx.x, t = threadIdx.x;
    __shared__ float p[CC];
    __shared__ float h[HID];
    if (t < CC) {
        float acc = 0.f;
        #pragma unroll
        for (int j = 0; j < CHUNKS_PER_N; ++j)
            acc += pp[(n * CHUNKS_PER_N + j) * CC + t];
        p[t] = acc * (1.0f / HWD);
    } else if (t < 128) {
        // wave 1: parallel sumexp reduction (49 lanes active)
        int l = t - 64;
        float v = (l < CHUNKS_PER_N) ? se[n * CHUNKS_PER_N + l] : 0.f;
        v = wave_sum(v);
        if (l == 0) scale[n] = GAMMA_F / v;
    }
    __syncthreads();
    if (t < HID) {
        float acc = b1[t];
        #pragma unroll 8
        for (int c = 0; c < CC; ++c) acc += p[c] * w1[c * HID + t];
        h[t] = fmaxf(acc, 0.f);
    }
    __syncthreads();
    float o = b2[t];
    #pragma unroll
    for (int j = 0; j < HID; ++j) o += h[j] * w2[j * OUTD + t];
    float theta = 2.f / (1.f + __expf(-o)) - 1.f;   // 2*sigmoid-1
    int k = t >> 7, c = (t >> 1) & 63, d = t & 1;
    float init = (k == 0) ? 1.f : 0.f;              // init_alpha==init_beta==[1,0]
    float lam = (d == 0) ? 1.f : 0.5f;              // LAMBDA_ALPHA / LAMBDA_BETA
    // packed layout per (n,c): {a0, b0, a1, b1} -> component index k*2 + d
    coef[(size_t)(n * CC + c) * 4 + k * 2 + d] = init + lam * theta;
}

// k3: pure streaming. 2D grid (784, N): n from blockIdx.y, one magic-div for
// the channel. One x float4 (L3-warm from k1) + one e float4 + one packed
// coef float4 (L1-hot, 64x reuse) -> 16 FLOPs -> nontemporal store.
__global__ __launch_bounds__(256) void k3_final(const float* __restrict__ x,
        const float* __restrict__ ews, const float* __restrict__ coef,
        const float* __restrict__ scale, float* __restrict__ out) {
    int n = blockIdx.y;
    unsigned r = blockIdx.x * 256u + threadIdx.x;   // < ROW4 exactly (784*256)
    unsigned c = r / HW4;                           // const-divisor magic mul
    unsigned g = r - c * HW4;
    size_t f = (size_t)n * ROW4 + r;

    float4 v = ((const float4*)x)[f];
    float4 e = ((const float4*)ews)[(size_t)n * HW4 + g];
    float4 cf = ((const float4*)coef)[n * CC + c];  // {a0,b0,a1,b1}
    float sc = scale[n];                            // L1-hot broadcast

    float spx = fminf(sc * e.x, 1.f);
    float spy = fminf(sc * e.y, 1.f);
    float spz = fminf(sc * e.z, 1.f);
    float spw = fminf(sc * e.w, 1.f);

    v4f r4;
    r4.x = spx * fmaxf(v.x * cf.x + cf.y, v.x * cf.z + cf.w);
    r4.y = spy * fmaxf(v.y * cf.x + cf.y, v.y * cf.z + cf.w);
    r4.z = spz * fmaxf(v.z * cf.x + cf.y, v.z * cf.z + cf.w);
    r4.w = spw * fmaxf(v.w * cf.x + cf.y, v.w * cf.z + cf.w);
    __builtin_nontemporal_store(r4, &((v4f*)out)[f]);
}

extern "C" void kernel_launch(void* const* d_in, const int* in_sizes, int n_in,
                              void* d_out, int out_size, void* d_ws, size_t ws_size,
                              hipStream_t stream) {
    const float* x      = (const float*)d_in[0];
    const float* conv_w = (const float*)d_in[1];
    const float* conv_b = (const float*)d_in[2];
    const float* w1     = (const float*)d_in[3];
    const float* b1     = (const float*)d_in[4];
    const float* w2     = (const float*)d_in[5];
    const float* b2     = (const float*)d_in[6];
    float* out = (float*)d_out;

    float* ws   = (float*)d_ws;
    float* pp   = ws;                       // NCHUNK*CC = 100352 floats
    float* se   = pp + NCHUNK * CC;         // NCHUNK   = 1568
    float* coef = se + NCHUNK;              // N*C*4    = 8192 (16B-aligned)
    float* scl  = coef + NN * CC * 4;       // 32
    float* ews  = scl + NN;                 // N*HWD    = 401408 (16B-aligned)

    k1_stats<<<NCHUNK, 64, 0, stream>>>(x, conv_w, conv_b, pp, se, ews);
    k2_mlp  <<<NN,    256, 0, stream>>>(pp, se, w1, b1, w2, b2, coef, scl);
    dim3 g3(ROW4 / 256, NN);
    k3_final<<<g3,    256, 0, stream>>>(x, ews, coef, scl, out);
}